// Round 3
// baseline (780.491 us; speedup 1.0000x reference)
//
#include <hip/hip_runtime.h>

#define Bg   128
#define NPG  512
#define EPGc 8192
#define Etot (Bg*EPGc)
#define DOUTc 10
#define K1c  410
#define K2c  328
#define N0c  (Bg*NPG)
#define N1c  (Bg*K1c)
#define N2c  (Bg*K2c)
#define EPSc 1e-5f

// ---------------- utility fills ----------------
static __global__ void k_fill_i32(int* p, int v, int n) {
  int i = blockIdx.x * 256 + threadIdx.x;
  if (i < n) p[i] = v;
}

static __global__ void k_fill_f32(float* p, float v, int n) {
  int i = blockIdx.x * 256 + threadIdx.x;
  if (i < n) p[i] = v;
}

// count in-degree (alive edges only; dst<0 = masked)
static __global__ void k_cnt(const int* __restrict__ dst, int* __restrict__ cnt, int e) {
  int i = blockIdx.x * 256 + threadIdx.x;
  if (i < e) { int d = dst[i]; if (d >= 0) atomicAdd(&cnt[d], 1); }
}

static __global__ void k_dinv(const int* __restrict__ cnt, float* __restrict__ dinv, int n) {
  int i = blockIdx.x * 256 + threadIdx.x;
  if (i < n) dinv[i] = 1.0f / sqrtf(1.0f + (float)cnt[i]);
}

// per-graph exclusive scan of counts -> row_ptr (nper+1 entries per graph)
static __global__ __launch_bounds__(512) void k_rowscan(const int* __restrict__ cnt,
                                                        int* __restrict__ rp, int nper) {
  __shared__ int sbuf[512];
  int g = blockIdx.x, tid = threadIdx.x;
  int v = (tid < nper) ? cnt[g * nper + tid] : 0;
  sbuf[tid] = v;
  __syncthreads();
  for (int off = 1; off < 512; off <<= 1) {
    int t = (tid >= off) ? sbuf[tid - off] : 0;
    __syncthreads();
    sbuf[tid] += t;
    __syncthreads();
  }
  if (tid < nper) rp[g * (nper + 1) + tid] = sbuf[tid] - v;   // exclusive
  if (tid == 511) rp[g * (nper + 1) + nper] = sbuf[511];      // total
}

// scatter edges into CSR slots (per-graph slot range [g*EPG,(g+1)*EPG))
static __global__ void k_fill_csr(const int* __restrict__ src, const int* __restrict__ dst,
                                  const float* __restrict__ dinv, const int* __restrict__ rp,
                                  int* __restrict__ fcnt, int* __restrict__ col,
                                  float* __restrict__ cval, int nper, int e) {
  int i = blockIdx.x * 256 + threadIdx.x;
  if (i >= e) return;
  int d = dst[i];
  if (d < 0) return;
  int s = src[i];
  int g = i >> 13;                       // EPG = 8192 edges per graph slot
  int local = d - g * nper;
  int pos = g * EPGc + rp[g * (nper + 1) + local] + atomicAdd(&fcnt[d], 1);
  col[pos] = s;
  cval[pos] = dinv[s] * dinv[d];
}

// ---------------- GEMM: Y[M x 128] = X[M x 128] @ W[128 x 128] ----------------
static __global__ __launch_bounds__(256) void k_gemm(const float* __restrict__ X,
                                                     const float* __restrict__ W,
                                                     float* __restrict__ Y, int M) {
  __shared__ float ws[128 * 128];      // 64 KB
  __shared__ float xsT[128][64];       // 32 KB, k-major
  int tid = threadIdx.x;
  for (int i = tid; i < 4096; i += 256) ((float4*)ws)[i] = ((const float4*)W)[i];
  int row0 = blockIdx.x * 64;
  for (int i = tid; i < 2048; i += 256) {
    int r = i >> 5, kq = i & 31;
    float4 v = ((const float4*)X)[(size_t)(row0 + r) * 32 + kq];
    int k = kq << 2;
    xsT[k][r] = v.x; xsT[k + 1][r] = v.y; xsT[k + 2][r] = v.z; xsT[k + 3][r] = v.w;
  }
  __syncthreads();
  int tx = tid & 15, ty = tid >> 4;    // thread tile: 4 rows x 8 cols
  float acc[4][8];
#pragma unroll
  for (int i = 0; i < 4; ++i)
#pragma unroll
    for (int j = 0; j < 8; ++j) acc[i][j] = 0.f;
#pragma unroll 4
  for (int k = 0; k < 128; ++k) {
    float4 xv = *(const float4*)&xsT[k][ty * 4];
    float4 wa = *(const float4*)&ws[k * 128 + tx * 8];
    float4 wb = *(const float4*)&ws[k * 128 + tx * 8 + 4];
    float xr[4] = {xv.x, xv.y, xv.z, xv.w};
    float wr[8] = {wa.x, wa.y, wa.z, wa.w, wb.x, wb.y, wb.z, wb.w};
#pragma unroll
    for (int i = 0; i < 4; ++i)
#pragma unroll
      for (int j = 0; j < 8; ++j) acc[i][j] += xr[i] * wr[j];
  }
#pragma unroll
  for (int i = 0; i < 4; ++i) {
    int row = row0 + ty * 4 + i;
    float4 o1 = make_float4(acc[i][0], acc[i][1], acc[i][2], acc[i][3]);
    float4 o2 = make_float4(acc[i][4], acc[i][5], acc[i][6], acc[i][7]);
    ((float4*)Y)[(size_t)row * 32 + tx * 2] = o1;
    ((float4*)Y)[(size_t)row * 32 + tx * 2 + 1] = o2;
  }
}

// GCN aggregation, LDS-staged (round-2 fix: gather from LDS, not L2).
// One block per (graph, feature-half). Stage nper x 64 slab (<=128 KB) into LDS,
// then 8 waves sweep dst rows; per edge: uniform s_load of col/cval + ds_read_b32
// (bank = lane%32 -> 2-way aliasing, free). Old version: 105 us, VALUBusy 9%,
// latency-bound on dependent col->row L2 gathers.
template <int NPER>
static __global__ __launch_bounds__(512) void k_agg2(const float* __restrict__ h0,
                                                     const float* __restrict__ dinv,
                                                     const float* __restrict__ bias,
                                                     const int* __restrict__ rp,
                                                     const int* __restrict__ col,
                                                     const float* __restrict__ cval,
                                                     float* __restrict__ h1) {
  __shared__ float hs[NPER * 64];      // 512 -> 128 KB, 410 -> 102.5 KB
  int g = blockIdx.x >> 1, half = blockIdx.x & 1, f0 = half * 64;
  int tid = threadIdx.x;
  for (int i = tid; i < NPER * 16; i += 512) {
    int node = i >> 4, fq = i & 15;
    ((float4*)hs)[i] = *(const float4*)&h0[((size_t)(g * NPER + node)) * 128 + f0 + fq * 4];
  }
  __syncthreads();
  int w = tid >> 6, l = tid & 63;
  float bsum = bias[f0 + l];
  const int*   cp = col  + (size_t)g * EPGc;
  const float* vp = cval + (size_t)g * EPGc;
  const int*   rpg = rp + g * (NPER + 1);
  for (int li = w; li < NPER; li += 8) {
    int j = g * NPER + li;
    int start = rpg[li], end = rpg[li + 1];
    float di = dinv[j];
    float acc = hs[li * 64 + l] * di * di + bsum;
    for (int e = start; e < end; ++e) {
      int s = cp[e] - g * NPER;        // graph-local src
      acc += hs[s * 64 + l] * vp[e];
    }
    h1[(size_t)j * 128 + f0 + l] = acc;
  }
}

// spre[i] = dot(h[i,:], w)   (one wave64 per node)
static __global__ __launch_bounds__(256) void k_gemv(const float* __restrict__ h,
                                                     const float* __restrict__ w,
                                                     float* __restrict__ out, int n) {
  int node = blockIdx.x * 4 + (threadIdx.x >> 6);
  int lane = threadIdx.x & 63;
  if (node >= n) return;
  float a = h[(size_t)node * 128 + lane] * w[lane] +
            h[(size_t)node * 128 + 64 + lane] * w[64 + lane];
  for (int off = 32; off > 0; off >>= 1) a += __shfl_xor(a, off, 64);
  if (lane == 0) out[node] = a;
}

// s[j] = spre[j]*dinv^2 + b + sum_e cval*spre[col]
static __global__ void k_score(const float* __restrict__ spre, const float* __restrict__ dinv,
                               const float* __restrict__ bptr, const int* __restrict__ rp,
                               const int* __restrict__ col, const float* __restrict__ cval,
                               float* __restrict__ s, int nper, int n) {
  int j = blockIdx.x * 256 + threadIdx.x;
  if (j >= n) return;
  int g = j / nper, li = j - g * nper;
  int start = g * EPGc + rp[g * (nper + 1) + li];
  int end   = g * EPGc + rp[g * (nper + 1) + li + 1];
  float di = dinv[j];
  float acc = spre[j] * di * di + bptr[0];
  for (int e = start; e < end; ++e) acc += spre[col[e]] * cval[e];
  s[j] = acc;
}

// per-graph top-K by bitonic sort of (score, idx) in LDS; only the SET matters downstream
template <int NPER, int K>
static __global__ __launch_bounds__(256) void k_topk(const float* __restrict__ s,
                                                     int* __restrict__ perm) {
  __shared__ float sc[512];
  __shared__ int   idx[512];
  int g = blockIdx.x, tid = threadIdx.x;
  for (int i = tid; i < 512; i += 256) {
    if (i < NPER) { sc[i] = s[g * NPER + i]; idx[i] = i; }
    else          { sc[i] = -3.402823466e38f; idx[i] = 0; }
  }
  __syncthreads();
  for (int kk = 2; kk <= 512; kk <<= 1) {
    for (int j = kk >> 1; j > 0; j >>= 1) {
      for (int base = 0; base < 512; base += 256) {
        int i = base + tid;
        int p = i ^ j;
        if (p > i) {
          bool up = ((i & kk) == 0);          // descending overall
          float si = sc[i], sp = sc[p];
          if (up ? (si < sp) : (si > sp)) {
            sc[i] = sp; sc[p] = si;
            int t = idx[i]; idx[i] = idx[p]; idx[p] = t;
          }
        }
      }
      __syncthreads();
    }
  }
  for (int r = tid; r < K; r += 256) perm[g * K + r] = g * NPER + idx[r];
}

static __global__ void k_remap_scatter(const int* __restrict__ perm, int* __restrict__ remap, int n) {
  int j = blockIdx.x * 256 + threadIdx.x;
  if (j < n) remap[perm[j]] = j;
}

static __global__ void k_edge_remap(const int* __restrict__ src, const int* __restrict__ dst,
                                    const int* __restrict__ remap, int* __restrict__ es,
                                    int* __restrict__ ed, int e) {
  int i = blockIdx.x * 256 + threadIdx.x;
  if (i >= e) return;
  int s2 = remap[src[i]];
  int d2 = remap[dst[i]];
  bool alive = (s2 >= 0) && (d2 >= 0);
  es[i] = alive ? s2 : -1;
  ed[i] = alive ? d2 : -1;
}

// xp[j] = relu(bn( h[perm[j]] * tanh(s[perm[j]]) ))
static __global__ __launch_bounds__(128) void k_pool_bn(const float* __restrict__ h,
                                                        const float* __restrict__ s,
                                                        const int* __restrict__ perm,
                                                        const float* __restrict__ gg,
                                                        const float* __restrict__ bb,
                                                        const float* __restrict__ mm,
                                                        const float* __restrict__ vv,
                                                        float* __restrict__ xp) {
  int j = blockIdx.x, f = threadIdx.x;
  int old = perm[j];
  float t = tanhf(s[old]);
  float val = h[(size_t)old * 128 + f] * t;
  float o = gg[f] * (val - mm[f]) / sqrtf(vv[f] + EPSc) + bb[f];
  xp[(size_t)j * 128 + f] = fmaxf(o, 0.0f);
}

// chunked segment-sum: grid = Bg * nchunk blocks of 128 threads.
static __global__ __launch_bounds__(128) void k_gsum2(const float* __restrict__ xp,
                                                      float* __restrict__ pooled,
                                                      int nper, int nchunk) {
  int g = blockIdx.x / nchunk, c = blockIdx.x - g * nchunk;
  int f = threadIdx.x;
  int rows = (nper + nchunk - 1) / nchunk;
  int r0 = c * rows;
  int r1 = min(nper, r0 + rows);
  if (r0 >= r1) return;
  float acc = 0.f;
  const float* p = xp + ((size_t)g * nper + r0) * 128 + f;
  for (int i = r0; i < r1; ++i, p += 128) acc += *p;
  atomicAdd(&pooled[g * 128 + f], acc);
}

static __global__ void k_final(const float* __restrict__ pooled,
                               const float* __restrict__ w0, const float* __restrict__ b0,
                               const float* __restrict__ w1, const float* __restrict__ b1,
                               const float* __restrict__ w2, const float* __restrict__ b2,
                               float* __restrict__ out) {
  int t = blockIdx.x * 256 + threadIdx.x;
  if (t >= Bg * DOUTc) return;
  int g = t / DOUTc, o = t - g * DOUTc;
  const float* p0 = pooled + g * 128;
  const float* p1 = pooled + Bg * 128 + g * 128;
  const float* p2 = pooled + 2 * Bg * 128 + g * 128;
  float acc = b0[o] + b1[o] + b2[o];
  for (int k = 0; k < 128; ++k)
    acc += p0[k] * w0[o * 128 + k] + p1[k] * w1[o * 128 + k] + p2[k] * w2[o * 128 + k];
  out[t] = acc;
}

extern "C" void kernel_launch(void* const* d_in, const int* in_sizes, int n_in,
                              void* d_out, int out_size, void* d_ws, size_t ws_size,
                              hipStream_t stream) {
  (void)in_sizes; (void)n_in; (void)out_size; (void)ws_size;
  const float* x    = (const float*)d_in[0];
  const int*   ei   = (const int*)d_in[1];
  const int*   src0 = ei;
  const int*   dst0 = ei + Etot;
  const float* c1W = (const float*)d_in[2];  const float* c1b = (const float*)d_in[3];
  const float* c2W = (const float*)d_in[4];  const float* c2b = (const float*)d_in[5];
  const float* s1W = (const float*)d_in[6];  const float* s1b = (const float*)d_in[7];
  const float* s2W = (const float*)d_in[8];  const float* s2b = (const float*)d_in[9];
  const float* bn1g = (const float*)d_in[10]; const float* bn1b = (const float*)d_in[11];
  const float* bn1m = (const float*)d_in[12]; const float* bn1v = (const float*)d_in[13];
  const float* bn2g = (const float*)d_in[14]; const float* bn2b = (const float*)d_in[15];
  const float* bn2m = (const float*)d_in[16]; const float* bn2v = (const float*)d_in[17];
  const float* l0W = (const float*)d_in[18]; const float* l0b = (const float*)d_in[19];
  const float* l1W = (const float*)d_in[20]; const float* l1b = (const float*)d_in[21];
  const float* l2W = (const float*)d_in[22]; const float* l2b = (const float*)d_in[23];
  float* out = (float*)d_out;

  char* p = (char*)d_ws;
  auto alloc = [&](size_t bytes) { char* q = p; p += (bytes + 255) & ~(size_t)255; return q; };
  float* h0    = (float*)alloc((size_t)N0c * 128 * 4);   // layer1 reuses as g1
  float* h1    = (float*)alloc((size_t)N0c * 128 * 4);   // layer1 reuses as h2
  float* xp1   = (float*)alloc((size_t)N1c * 128 * 4);
  float* xp2   = (float*)alloc((size_t)N2c * 128 * 4);
  int*   cnt   = (int*)alloc((size_t)N0c * 4);
  int*   fcnt  = (int*)alloc((size_t)N0c * 4);
  float* dinv  = (float*)alloc((size_t)N0c * 4);
  int*   rp    = (int*)alloc((size_t)Bg * (NPG + 1) * 4);
  int*   col   = (int*)alloc((size_t)Etot * 4);
  float* cval  = (float*)alloc((size_t)Etot * 4);
  float* spre  = (float*)alloc((size_t)N0c * 4);
  float* sv    = (float*)alloc((size_t)N0c * 4);
  int*   perm  = (int*)alloc((size_t)N1c * 4);
  int*   remap = (int*)alloc((size_t)N0c * 4);
  int*   es    = (int*)alloc((size_t)Etot * 4);
  int*   ed    = (int*)alloc((size_t)Etot * 4);
  float* pooled= (float*)alloc((size_t)3 * Bg * 128 * 4);

  dim3 b256(256), b128(128), b512(512);
  int gE = (Etot + 255) / 256;

  // ---------------- layer 0 ----------------
  k_fill_i32<<<(N0c + 255) / 256, b256, 0, stream>>>(cnt, 0, N0c);
  k_fill_f32<<<(3 * Bg * 128 + 255) / 256, b256, 0, stream>>>(pooled, 0.f, 3 * Bg * 128);
  k_cnt<<<gE, b256, 0, stream>>>(dst0, cnt, Etot);
  k_dinv<<<(N0c + 255) / 256, b256, 0, stream>>>(cnt, dinv, N0c);
  k_rowscan<<<Bg, b512, 0, stream>>>(cnt, rp, NPG);
  k_fill_i32<<<(N0c + 255) / 256, b256, 0, stream>>>(fcnt, 0, N0c);
  k_fill_csr<<<gE, b256, 0, stream>>>(src0, dst0, dinv, rp, fcnt, col, cval, NPG, Etot);
  k_gemm<<<N0c / 64, b256, 0, stream>>>(x, c1W, h0, N0c);
  k_agg2<NPG><<<Bg * 2, b512, 0, stream>>>(h0, dinv, c1b, rp, col, cval, h1);
  k_gemv<<<(N0c + 3) / 4, b256, 0, stream>>>(h1, s1W, spre, N0c);
  k_score<<<(N0c + 255) / 256, b256, 0, stream>>>(spre, dinv, s1b, rp, col, cval, sv, NPG, N0c);
  k_topk<NPG, K1c><<<Bg, b256, 0, stream>>>(sv, perm);
  k_fill_i32<<<(N0c + 255) / 256, b256, 0, stream>>>(remap, -1, N0c);
  k_remap_scatter<<<(N1c + 255) / 256, b256, 0, stream>>>(perm, remap, N1c);
  k_edge_remap<<<gE, b256, 0, stream>>>(src0, dst0, remap, es, ed, Etot);
  k_pool_bn<<<N1c, b128, 0, stream>>>(h1, sv, perm, bn1g, bn1b, bn1m, bn1v, xp1);

  // ---------------- layer 1 ----------------
  k_fill_i32<<<(N1c + 255) / 256, b256, 0, stream>>>(cnt, 0, N1c);
  k_cnt<<<gE, b256, 0, stream>>>(ed, cnt, Etot);
  k_dinv<<<(N1c + 255) / 256, b256, 0, stream>>>(cnt, dinv, N1c);
  k_rowscan<<<Bg, b512, 0, stream>>>(cnt, rp, K1c);
  k_fill_i32<<<(N1c + 255) / 256, b256, 0, stream>>>(fcnt, 0, N1c);
  k_fill_csr<<<gE, b256, 0, stream>>>(es, ed, dinv, rp, fcnt, col, cval, K1c, Etot);
  float* g1 = h0;   // h0 dead after layer-0 agg
  float* h2 = h1;   // h1 dead after pool_bn
  k_gemm<<<N1c / 64, b256, 0, stream>>>(xp1, c2W, g1, N1c);
  k_agg2<K1c><<<Bg * 2, b512, 0, stream>>>(g1, dinv, c2b, rp, col, cval, h2);
  k_gemv<<<(N1c + 3) / 4, b256, 0, stream>>>(h2, s2W, spre, N1c);
  k_score<<<(N1c + 255) / 256, b256, 0, stream>>>(spre, dinv, s2b, rp, col, cval, sv, K1c, N1c);
  k_topk<K1c, K2c><<<Bg, b256, 0, stream>>>(sv, perm);
  k_pool_bn<<<N2c, b128, 0, stream>>>(h2, sv, perm, bn2g, bn2b, bn2m, bn2v, xp2);

  // ---------------- readout (chunked, atomic combine) ----------------
  k_gsum2<<<Bg * 16, b128, 0, stream>>>(x, pooled, NPG, 16);
  k_gsum2<<<Bg * 16, b128, 0, stream>>>(xp1, pooled + Bg * 128, K1c, 16);
  k_gsum2<<<Bg * 16, b128, 0, stream>>>(xp2, pooled + 2 * Bg * 128, K2c, 16);
  k_final<<<(Bg * DOUTc + 255) / 256, b256, 0, stream>>>(pooled, l0W, l0b, l1W, l1b, l2W, l2b, out);
}

// Round 4
// 534.098 us; speedup vs baseline: 1.4613x; 1.4613x over previous
//
#include <hip/hip_runtime.h>

#define Bg   128
#define NPG  512
#define EPGc 8192
#define Etot (Bg*EPGc)
#define DOUTc 10
#define K1c  410
#define K2c  328
#define N0c  (Bg*NPG)
#define N1c  (Bg*K1c)
#define N2c  (Bg*K2c)
#define EPSc 1e-5f

// one-shot init: cnt=0, remap=-1, pooled=0
static __global__ void k_init(int* __restrict__ cnt, int* __restrict__ remap,
                              float* __restrict__ pooled) {
  int i = blockIdx.x * 256 + threadIdx.x;
  if (i < N0c) { cnt[i] = 0; remap[i] = -1; }
  if (i < 3 * Bg * 128) pooled[i] = 0.f;
}

// count in-degree (alive edges only; dst<0 = masked)
static __global__ void k_cnt(const int* __restrict__ dst, int* __restrict__ cnt, int e) {
  int i = blockIdx.x * 256 + threadIdx.x;
  if (i < e) { int d = dst[i]; if (d >= 0) atomicAdd(&cnt[d], 1); }
}

static __global__ void k_dinv(const int* __restrict__ cnt, float* __restrict__ dinv, int n) {
  int i = blockIdx.x * 256 + threadIdx.x;
  if (i < n) dinv[i] = 1.0f / sqrtf(1.0f + (float)cnt[i]);
}

// per-graph exclusive scan of counts -> row_ptr; also re-zeroes cnt for reuse as scatter counter
static __global__ __launch_bounds__(512) void k_rowscan(int* __restrict__ cnt,
                                                        int* __restrict__ rp, int nper) {
  __shared__ int sbuf[512];
  int g = blockIdx.x, tid = threadIdx.x;
  int v = (tid < nper) ? cnt[g * nper + tid] : 0;
  sbuf[tid] = v;
  __syncthreads();
  for (int off = 1; off < 512; off <<= 1) {
    int t = (tid >= off) ? sbuf[tid - off] : 0;
    __syncthreads();
    sbuf[tid] += t;
    __syncthreads();
  }
  if (tid < nper) { rp[g * (nper + 1) + tid] = sbuf[tid] - v; cnt[g * nper + tid] = 0; }
  if (tid == 511) rp[g * (nper + 1) + nper] = sbuf[511];
}

// scatter edges into CSR slots; packed edge record {col, cval} -> one 8B load downstream
static __global__ void k_fill_csr(const int* __restrict__ src, const int* __restrict__ dst,
                                  const float* __restrict__ dinv, const int* __restrict__ rp,
                                  int* __restrict__ fcnt, int2* __restrict__ e2,
                                  int nper, int e) {
  int i = blockIdx.x * 256 + threadIdx.x;
  if (i >= e) return;
  int d = dst[i];
  if (d < 0) return;
  int s = src[i];
  int g = i >> 13;                       // EPG = 8192 edges per graph slot
  int local = d - g * nper;
  int pos = g * EPGc + rp[g * (nper + 1) + local] + atomicAdd(&fcnt[d], 1);
  e2[pos] = make_int2(s, __float_as_int(dinv[s] * dinv[d]));
}

// ---------------- GEMM: Y[M x 128] = X[M x 128] @ W[128 x 128] ----------------
static __global__ __launch_bounds__(256) void k_gemm(const float* __restrict__ X,
                                                     const float* __restrict__ W,
                                                     float* __restrict__ Y, int M) {
  __shared__ float ws[128 * 128];      // 64 KB
  __shared__ float xsT[128][64];       // 32 KB, k-major
  int tid = threadIdx.x;
  for (int i = tid; i < 4096; i += 256) ((float4*)ws)[i] = ((const float4*)W)[i];
  int row0 = blockIdx.x * 64;
  for (int i = tid; i < 2048; i += 256) {
    int r = i >> 5, kq = i & 31;
    float4 v = ((const float4*)X)[(size_t)(row0 + r) * 32 + kq];
    int k = kq << 2;
    xsT[k][r] = v.x; xsT[k + 1][r] = v.y; xsT[k + 2][r] = v.z; xsT[k + 3][r] = v.w;
  }
  __syncthreads();
  int tx = tid & 15, ty = tid >> 4;    // thread tile: 4 rows x 8 cols
  float acc[4][8];
#pragma unroll
  for (int i = 0; i < 4; ++i)
#pragma unroll
    for (int j = 0; j < 8; ++j) acc[i][j] = 0.f;
#pragma unroll 4
  for (int k = 0; k < 128; ++k) {
    float4 xv = *(const float4*)&xsT[k][ty * 4];
    float4 wa = *(const float4*)&ws[k * 128 + tx * 8];
    float4 wb = *(const float4*)&ws[k * 128 + tx * 8 + 4];
    float xr[4] = {xv.x, xv.y, xv.z, xv.w};
    float wr[8] = {wa.x, wa.y, wa.z, wa.w, wb.x, wb.y, wb.z, wb.w};
#pragma unroll
    for (int i = 0; i < 4; ++i)
#pragma unroll
      for (int j = 0; j < 8; ++j) acc[i][j] += xr[i] * wr[j];
  }
#pragma unroll
  for (int i = 0; i < 4; ++i) {
    int row = row0 + ty * 4 + i;
    float4 o1 = make_float4(acc[i][0], acc[i][1], acc[i][2], acc[i][3]);
    float4 o2 = make_float4(acc[i][4], acc[i][5], acc[i][6], acc[i][7]);
    ((float4*)Y)[(size_t)row * 32 + tx * 2] = o1;
    ((float4*)Y)[(size_t)row * 32 + tx * 2 + 1] = o2;
  }
}

// GCN aggregation, round-3: high-occupancy L2 gather with 4x edge MLP.
// Half-wave (32 lanes x float4) per dst row; packed int2 edge recs; x4 unroll keeps
// 4 edge-descriptor loads + 4 row gathers in flight (round-2/3 versions were a serial
// 1-edge chain: 105us @80%occ / 163us @21%occ). XCD swizzle: all blocks of a graph on
// one XCD -> its 256KB h-slice stays L2-resident (16 graphs x 256KB = 4MB/XCD).
// Epilogue fuses the score GEMV: spre[j] = dot(h1[j,:], sw) (row already in regs).
template <int NPER, int RG>
static __global__ __launch_bounds__(256) void k_agg3(const float* __restrict__ h0,
                                                     const float* __restrict__ dinv,
                                                     const float* __restrict__ bias,
                                                     const int* __restrict__ rp,
                                                     const int2* __restrict__ e2,
                                                     const float* __restrict__ sw,
                                                     float* __restrict__ h1,
                                                     float* __restrict__ spre) {
  int tid = threadIdx.x;
  int hw = tid >> 5, l = tid & 31;
  int b = blockIdx.x;
  int xcd = b & 7, slot = b >> 3;
  int g = xcd * 16 + (slot & 15);
  int rowgrp = slot >> 4;                 // [0, RG)
  int li = rowgrp * 8 + hw;
  if (li >= NPER) return;
  int j = g * NPER + li;
  const int* rpg = rp + g * (NPER + 1);
  int start = rpg[li], end = rpg[li + 1];
  const int2* ep = e2 + (size_t)g * EPGc;
  float di = dinv[j];
  float sc = di * di;
  float4 acc = *(const float4*)&h0[(size_t)j * 128 + l * 4];
  float4 bb = ((const float4*)bias)[l];
  acc.x = acc.x * sc + bb.x; acc.y = acc.y * sc + bb.y;
  acc.z = acc.z * sc + bb.z; acc.w = acc.w * sc + bb.w;
  int e = start;
  for (; e + 4 <= end; e += 4) {
    int2 p0 = ep[e], p1 = ep[e + 1], p2 = ep[e + 2], p3 = ep[e + 3];
    float4 v0 = *(const float4*)&h0[(size_t)p0.x * 128 + l * 4];
    float4 v1 = *(const float4*)&h0[(size_t)p1.x * 128 + l * 4];
    float4 v2 = *(const float4*)&h0[(size_t)p2.x * 128 + l * 4];
    float4 v3 = *(const float4*)&h0[(size_t)p3.x * 128 + l * 4];
    float c0 = __int_as_float(p0.y), c1 = __int_as_float(p1.y);
    float c2 = __int_as_float(p2.y), c3 = __int_as_float(p3.y);
    acc.x += v0.x * c0 + v1.x * c1 + v2.x * c2 + v3.x * c3;
    acc.y += v0.y * c0 + v1.y * c1 + v2.y * c2 + v3.y * c3;
    acc.z += v0.z * c0 + v1.z * c1 + v2.z * c2 + v3.z * c3;
    acc.w += v0.w * c0 + v1.w * c1 + v2.w * c2 + v3.w * c3;
  }
  for (; e < end; ++e) {
    int2 pp = ep[e];
    float c = __int_as_float(pp.y);
    float4 v = *(const float4*)&h0[(size_t)pp.x * 128 + l * 4];
    acc.x += v.x * c; acc.y += v.y * c; acc.z += v.z * c; acc.w += v.w * c;
  }
  ((float4*)&h1[(size_t)j * 128])[l] = acc;
  // fused score GEMV
  float4 w4 = ((const float4*)sw)[l];
  float pr = acc.x * w4.x + acc.y * w4.y + acc.z * w4.z + acc.w * w4.w;
#pragma unroll
  for (int off = 16; off; off >>= 1) pr += __shfl_xor(pr, off, 64);
  if (l == 0) spre[j] = pr;
}

// s[j] = spre[j]*dinv^2 + b + sum_e cval*spre[col]  (x4 unrolled, packed edges)
template <int NPER>
static __global__ void k_score2(const float* __restrict__ spre, const float* __restrict__ dinv,
                                const float* __restrict__ bptr, const int* __restrict__ rp,
                                const int2* __restrict__ e2, float* __restrict__ s, int n) {
  int j = blockIdx.x * 256 + threadIdx.x;
  if (j >= n) return;
  int g = j / NPER, li = j - g * NPER;
  const int* rpg = rp + g * (NPER + 1);
  int start = rpg[li], end = rpg[li + 1];
  const int2* ep = e2 + (size_t)g * EPGc;
  float di = dinv[j];
  float acc = spre[j] * di * di + bptr[0];
  int e = start;
  for (; e + 4 <= end; e += 4) {
    int2 p0 = ep[e], p1 = ep[e + 1], p2 = ep[e + 2], p3 = ep[e + 3];
    float a0 = spre[p0.x], a1 = spre[p1.x], a2 = spre[p2.x], a3 = spre[p3.x];
    acc += a0 * __int_as_float(p0.y) + a1 * __int_as_float(p1.y) +
           a2 * __int_as_float(p2.y) + a3 * __int_as_float(p3.y);
  }
  for (; e < end; ++e) { int2 pp = ep[e]; acc += spre[pp.x] * __int_as_float(pp.y); }
  s[j] = acc;
}

// per-graph top-K by bitonic sort of (score, idx) in LDS; only the SET matters downstream
template <int NPER, int K>
static __global__ __launch_bounds__(256) void k_topk(const float* __restrict__ s,
                                                     int* __restrict__ perm) {
  __shared__ float sc[512];
  __shared__ int   idx[512];
  int g = blockIdx.x, tid = threadIdx.x;
  for (int i = tid; i < 512; i += 256) {
    if (i < NPER) { sc[i] = s[g * NPER + i]; idx[i] = i; }
    else          { sc[i] = -3.402823466e38f; idx[i] = 0; }
  }
  __syncthreads();
  for (int kk = 2; kk <= 512; kk <<= 1) {
    for (int j = kk >> 1; j > 0; j >>= 1) {
      for (int base = 0; base < 512; base += 256) {
        int i = base + tid;
        int p = i ^ j;
        if (p > i) {
          bool up = ((i & kk) == 0);          // descending overall
          float si = sc[i], sp = sc[p];
          if (up ? (si < sp) : (si > sp)) {
            sc[i] = sp; sc[p] = si;
            int t = idx[i]; idx[i] = idx[p]; idx[p] = t;
          }
        }
      }
      __syncthreads();
    }
  }
  for (int r = tid; r < K; r += 256) perm[g * K + r] = g * NPER + idx[r];
}

static __global__ void k_remap_scatter(const int* __restrict__ perm, int* __restrict__ remap, int n) {
  int j = blockIdx.x * 256 + threadIdx.x;
  if (j < n) remap[perm[j]] = j;
}

static __global__ void k_edge_remap(const int* __restrict__ src, const int* __restrict__ dst,
                                    const int* __restrict__ remap, int* __restrict__ es,
                                    int* __restrict__ ed, int e) {
  int i = blockIdx.x * 256 + threadIdx.x;
  if (i >= e) return;
  int s2 = remap[src[i]];
  int d2 = remap[dst[i]];
  bool alive = (s2 >= 0) && (d2 >= 0);
  es[i] = alive ? s2 : -1;
  ed[i] = alive ? d2 : -1;
}

// xp[j] = relu(bn( h[perm[j]] * tanh(s[perm[j]]) )); also re-zeroes cnt[j] for next layer
static __global__ __launch_bounds__(128) void k_pool_bn(const float* __restrict__ h,
                                                        const float* __restrict__ s,
                                                        const int* __restrict__ perm,
                                                        const float* __restrict__ gg,
                                                        const float* __restrict__ bb,
                                                        const float* __restrict__ mm,
                                                        const float* __restrict__ vv,
                                                        float* __restrict__ xp,
                                                        int* __restrict__ cnt) {
  int j = blockIdx.x, f = threadIdx.x;
  int old = perm[j];
  float t = tanhf(s[old]);
  float val = h[(size_t)old * 128 + f] * t;
  float o = gg[f] * (val - mm[f]) / sqrtf(vv[f] + EPSc) + bb[f];
  xp[(size_t)j * 128 + f] = fmaxf(o, 0.0f);
  if (f == 0) cnt[j] = 0;
}

// chunked segment-sum
static __global__ __launch_bounds__(128) void k_gsum2(const float* __restrict__ xp,
                                                      float* __restrict__ pooled,
                                                      int nper, int nchunk) {
  int g = blockIdx.x / nchunk, c = blockIdx.x - g * nchunk;
  int f = threadIdx.x;
  int rows = (nper + nchunk - 1) / nchunk;
  int r0 = c * rows;
  int r1 = min(nper, r0 + rows);
  if (r0 >= r1) return;
  float acc = 0.f;
  const float* p = xp + ((size_t)g * nper + r0) * 128 + f;
  for (int i = r0; i < r1; ++i, p += 128) acc += *p;
  atomicAdd(&pooled[g * 128 + f], acc);
}

static __global__ void k_final(const float* __restrict__ pooled,
                               const float* __restrict__ w0, const float* __restrict__ b0,
                               const float* __restrict__ w1, const float* __restrict__ b1,
                               const float* __restrict__ w2, const float* __restrict__ b2,
                               float* __restrict__ out) {
  int t = blockIdx.x * 256 + threadIdx.x;
  if (t >= Bg * DOUTc) return;
  int g = t / DOUTc, o = t - g * DOUTc;
  const float* p0 = pooled + g * 128;
  const float* p1 = pooled + Bg * 128 + g * 128;
  const float* p2 = pooled + 2 * Bg * 128 + g * 128;
  float acc = b0[o] + b1[o] + b2[o];
  for (int k = 0; k < 128; ++k)
    acc += p0[k] * w0[o * 128 + k] + p1[k] * w1[o * 128 + k] + p2[k] * w2[o * 128 + k];
  out[t] = acc;
}

extern "C" void kernel_launch(void* const* d_in, const int* in_sizes, int n_in,
                              void* d_out, int out_size, void* d_ws, size_t ws_size,
                              hipStream_t stream) {
  (void)in_sizes; (void)n_in; (void)out_size; (void)ws_size;
  const float* x    = (const float*)d_in[0];
  const int*   ei   = (const int*)d_in[1];
  const int*   src0 = ei;
  const int*   dst0 = ei + Etot;
  const float* c1W = (const float*)d_in[2];  const float* c1b = (const float*)d_in[3];
  const float* c2W = (const float*)d_in[4];  const float* c2b = (const float*)d_in[5];
  const float* s1W = (const float*)d_in[6];  const float* s1b = (const float*)d_in[7];
  const float* s2W = (const float*)d_in[8];  const float* s2b = (const float*)d_in[9];
  const float* bn1g = (const float*)d_in[10]; const float* bn1b = (const float*)d_in[11];
  const float* bn1m = (const float*)d_in[12]; const float* bn1v = (const float*)d_in[13];
  const float* bn2g = (const float*)d_in[14]; const float* bn2b = (const float*)d_in[15];
  const float* bn2m = (const float*)d_in[16]; const float* bn2v = (const float*)d_in[17];
  const float* l0W = (const float*)d_in[18]; const float* l0b = (const float*)d_in[19];
  const float* l1W = (const float*)d_in[20]; const float* l1b = (const float*)d_in[21];
  const float* l2W = (const float*)d_in[22]; const float* l2b = (const float*)d_in[23];
  float* out = (float*)d_out;

  char* p = (char*)d_ws;
  auto alloc = [&](size_t bytes) { char* q = p; p += (bytes + 255) & ~(size_t)255; return q; };
  float* h0    = (float*)alloc((size_t)N0c * 128 * 4);   // layer1 reuses as g1
  float* h1    = (float*)alloc((size_t)N0c * 128 * 4);   // layer1 reuses as h2
  float* xp1   = (float*)alloc((size_t)N1c * 128 * 4);
  float* xp2   = (float*)alloc((size_t)N2c * 128 * 4);
  int*   cnt   = (int*)alloc((size_t)N0c * 4);           // also the CSR scatter counter
  float* dinv  = (float*)alloc((size_t)N0c * 4);
  int*   rp    = (int*)alloc((size_t)Bg * (NPG + 1) * 4);
  int2*  e2    = (int2*)alloc((size_t)Etot * 8);
  float* spre  = (float*)alloc((size_t)N0c * 4);
  float* sv    = (float*)alloc((size_t)N0c * 4);
  int*   perm  = (int*)alloc((size_t)N1c * 4);
  int*   remap = (int*)alloc((size_t)N0c * 4);
  int*   es    = (int*)alloc((size_t)Etot * 4);
  int*   ed    = (int*)alloc((size_t)Etot * 4);
  float* pooled= (float*)alloc((size_t)3 * Bg * 128 * 4);

  dim3 b256(256), b128(128), b512(512);
  int gE = (Etot + 255) / 256;

  // ---------------- layer 0 ----------------
  k_init<<<(N0c + 255) / 256, b256, 0, stream>>>(cnt, remap, pooled);
  k_cnt<<<gE, b256, 0, stream>>>(dst0, cnt, Etot);
  k_dinv<<<(N0c + 255) / 256, b256, 0, stream>>>(cnt, dinv, N0c);
  k_rowscan<<<Bg, b512, 0, stream>>>(cnt, rp, NPG);            // zeroes cnt
  k_fill_csr<<<gE, b256, 0, stream>>>(src0, dst0, dinv, rp, cnt, e2, NPG, Etot);
  k_gemm<<<N0c / 64, b256, 0, stream>>>(x, c1W, h0, N0c);
  k_agg3<NPG, 64><<<128 * 64, b256, 0, stream>>>(h0, dinv, c1b, rp, e2, s1W, h1, spre);
  k_score2<NPG><<<(N0c + 255) / 256, b256, 0, stream>>>(spre, dinv, s1b, rp, e2, sv, N0c);
  k_topk<NPG, K1c><<<Bg, b256, 0, stream>>>(sv, perm);
  k_remap_scatter<<<(N1c + 255) / 256, b256, 0, stream>>>(perm, remap, N1c);
  k_edge_remap<<<gE, b256, 0, stream>>>(src0, dst0, remap, es, ed, Etot);
  k_pool_bn<<<N1c, b128, 0, stream>>>(h1, sv, perm, bn1g, bn1b, bn1m, bn1v, xp1, cnt);

  // ---------------- layer 1 ----------------
  k_cnt<<<gE, b256, 0, stream>>>(ed, cnt, Etot);               // cnt zeroed by pool_bn
  k_dinv<<<(N1c + 255) / 256, b256, 0, stream>>>(cnt, dinv, N1c);
  k_rowscan<<<Bg, b512, 0, stream>>>(cnt, rp, K1c);            // zeroes cnt
  k_fill_csr<<<gE, b256, 0, stream>>>(es, ed, dinv, rp, cnt, e2, K1c, Etot);
  float* g1 = h0;   // h0 dead after layer-0 agg
  float* h2 = h1;   // h1 dead after pool_bn
  k_gemm<<<N1c / 64, b256, 0, stream>>>(xp1, c2W, g1, N1c);
  k_agg3<K1c, 52><<<128 * 52, b256, 0, stream>>>(g1, dinv, c2b, rp, e2, s2W, h2, spre);
  k_score2<K1c><<<(N1c + 255) / 256, b256, 0, stream>>>(spre, dinv, s2b, rp, e2, sv, N1c);
  k_topk<K1c, K2c><<<Bg, b256, 0, stream>>>(sv, perm);
  k_pool_bn<<<N2c, b128, 0, stream>>>(h2, sv, perm, bn2g, bn2b, bn2m, bn2v, xp2, cnt);

  // ---------------- readout ----------------
  k_gsum2<<<Bg * 16, b128, 0, stream>>>(x, pooled, NPG, 16);
  k_gsum2<<<Bg * 16, b128, 0, stream>>>(xp1, pooled + Bg * 128, K1c, 16);
  k_gsum2<<<Bg * 16, b128, 0, stream>>>(xp2, pooled + 2 * Bg * 128, K2c, 16);
  k_final<<<(Bg * DOUTc + 255) / 256, b256, 0, stream>>>(pooled, l0W, l0b, l1W, l1b, l2W, l2b, out);
}

// Round 5
// 480.862 us; speedup vs baseline: 1.6231x; 1.1107x over previous
//
#include <hip/hip_runtime.h>

#define Bg   128
#define NPG  512
#define EPGc 8192
#define Etot (Bg*EPGc)
#define DOUTc 10
#define K1c  410
#define K2c  328
#define N0c  (Bg*NPG)
#define N1c  (Bg*K1c)
#define N2c  (Bg*K2c)
#define EPSc 1e-5f

// one-shot init: cnt=0, remap=-1, pooled=0
static __global__ void k_init(int* __restrict__ cnt, int* __restrict__ remap,
                              float* __restrict__ pooled) {
  int i = blockIdx.x * 256 + threadIdx.x;
  if (i < N0c) { cnt[i] = 0; remap[i] = -1; }
  if (i < 3 * Bg * 128) pooled[i] = 0.f;
}

// count in-degree (alive edges only; dst<0 = masked)
static __global__ void k_cnt(const int* __restrict__ dst, int* __restrict__ cnt, int e) {
  int i = blockIdx.x * 256 + threadIdx.x;
  if (i < e) { int d = dst[i]; if (d >= 0) atomicAdd(&cnt[d], 1); }
}

static __global__ void k_dinv(const int* __restrict__ cnt, float* __restrict__ dinv, int n) {
  int i = blockIdx.x * 256 + threadIdx.x;
  if (i < n) dinv[i] = 1.0f / sqrtf(1.0f + (float)cnt[i]);
}

// per-graph exclusive scan of counts -> row_ptr; also re-zeroes cnt for reuse as scatter counter
static __global__ __launch_bounds__(512) void k_rowscan(int* __restrict__ cnt,
                                                        int* __restrict__ rp, int nper) {
  __shared__ int sbuf[512];
  int g = blockIdx.x, tid = threadIdx.x;
  int v = (tid < nper) ? cnt[g * nper + tid] : 0;
  sbuf[tid] = v;
  __syncthreads();
  for (int off = 1; off < 512; off <<= 1) {
    int t = (tid >= off) ? sbuf[tid - off] : 0;
    __syncthreads();
    sbuf[tid] += t;
    __syncthreads();
  }
  if (tid < nper) { rp[g * (nper + 1) + tid] = sbuf[tid] - v; cnt[g * nper + tid] = 0; }
  if (tid == 511) rp[g * (nper + 1) + nper] = sbuf[511];
}

// scatter edges into CSR slots; packed edge record {col, cval} -> one 8B load downstream
static __global__ void k_fill_csr(const int* __restrict__ src, const int* __restrict__ dst,
                                  const float* __restrict__ dinv, const int* __restrict__ rp,
                                  int* __restrict__ fcnt, int2* __restrict__ e2,
                                  int nper, int e) {
  int i = blockIdx.x * 256 + threadIdx.x;
  if (i >= e) return;
  int d = dst[i];
  if (d < 0) return;
  int s = src[i];
  int g = i >> 13;                       // EPG = 8192 edges per graph slot
  int local = d - g * nper;
  int pos = g * EPGc + rp[g * (nper + 1) + local] + atomicAdd(&fcnt[d], 1);
  e2[pos] = make_int2(s, __float_as_int(dinv[s] * dinv[d]));
}

// ---------------- GEMM: Y[M x 128] = X[M x 128] @ W[128 x 128] ----------------
// Round-4 rewrite. Old version: 70us, 1.23e7 bank conflicts (32-way on the
// k-major transpose staging), 4 waves/CU. Now: 512 thr, 128-row tile, X staged
// row-major with +4 pad (inner reads 2-way = free), W flat; k-unroll x4 ->
// VALU-bound (~256 FMA cyc vs ~200 LDS cyc per chunk); 8 waves/CU overlap.
static __global__ __launch_bounds__(512) void k_gemm2(const float* __restrict__ X,
                                                      const float* __restrict__ W,
                                                      float* __restrict__ Y, int M) {
  __shared__ float ws[128 * 128];      // 64 KB, [k][n]
  __shared__ float xs[128 * 132];      // 66 KB, [r][k] padded +4
  int tid = threadIdx.x;
  for (int i = tid; i < 4096; i += 512) ((float4*)ws)[i] = ((const float4*)W)[i];
  int row0 = blockIdx.x * 128;
  for (int i = tid; i < 4096; i += 512) {
    int r = i >> 5, kq = i & 31;
    float4 v = ((const float4*)X)[(size_t)(row0 + r) * 32 + kq];
    *(float4*)&xs[r * 132 + kq * 4] = v;
  }
  __syncthreads();
  int tx = tid & 15, ty = tid >> 4;    // ty 0..31: rows ty*4..+3; tx: cols tx*8..+7
  float acc[4][8];
#pragma unroll
  for (int i = 0; i < 4; ++i)
#pragma unroll
    for (int j = 0; j < 8; ++j) acc[i][j] = 0.f;
  for (int k = 0; k < 128; k += 4) {
    float4 xr[4];
#pragma unroll
    for (int i = 0; i < 4; ++i) xr[i] = *(const float4*)&xs[(ty * 4 + i) * 132 + k];
    const float* xf = (const float*)xr;
#pragma unroll
    for (int kk = 0; kk < 4; ++kk) {
      float4 wa = *(const float4*)&ws[(k + kk) * 128 + tx * 8];
      float4 wb = *(const float4*)&ws[(k + kk) * 128 + tx * 8 + 4];
      float wr[8] = {wa.x, wa.y, wa.z, wa.w, wb.x, wb.y, wb.z, wb.w};
#pragma unroll
      for (int i = 0; i < 4; ++i) {
        float xv = xf[i * 4 + kk];
#pragma unroll
        for (int j = 0; j < 8; ++j) acc[i][j] += xv * wr[j];
      }
    }
  }
#pragma unroll
  for (int i = 0; i < 4; ++i) {
    int row = row0 + ty * 4 + i;
    float4 o1 = make_float4(acc[i][0], acc[i][1], acc[i][2], acc[i][3]);
    float4 o2 = make_float4(acc[i][4], acc[i][5], acc[i][6], acc[i][7]);
    ((float4*)Y)[(size_t)row * 32 + tx * 2] = o1;
    ((float4*)Y)[(size_t)row * 32 + tx * 2 + 1] = o2;
  }
}

// GCN aggregation: high-occupancy L2 gather with 4x edge MLP + fused score GEMV.
template <int NPER, int RG>
static __global__ __launch_bounds__(256) void k_agg3(const float* __restrict__ h0,
                                                     const float* __restrict__ dinv,
                                                     const float* __restrict__ bias,
                                                     const int* __restrict__ rp,
                                                     const int2* __restrict__ e2,
                                                     const float* __restrict__ sw,
                                                     float* __restrict__ h1,
                                                     float* __restrict__ spre) {
  int tid = threadIdx.x;
  int hw = tid >> 5, l = tid & 31;
  int b = blockIdx.x;
  int xcd = b & 7, slot = b >> 3;
  int g = xcd * 16 + (slot & 15);
  int rowgrp = slot >> 4;                 // [0, RG)
  int li = rowgrp * 8 + hw;
  if (li >= NPER) return;
  int j = g * NPER + li;
  const int* rpg = rp + g * (NPER + 1);
  int start = rpg[li], end = rpg[li + 1];
  const int2* ep = e2 + (size_t)g * EPGc;
  float di = dinv[j];
  float sc = di * di;
  float4 acc = *(const float4*)&h0[(size_t)j * 128 + l * 4];
  float4 bb = ((const float4*)bias)[l];
  acc.x = acc.x * sc + bb.x; acc.y = acc.y * sc + bb.y;
  acc.z = acc.z * sc + bb.z; acc.w = acc.w * sc + bb.w;
  int e = start;
  for (; e + 4 <= end; e += 4) {
    int2 p0 = ep[e], p1 = ep[e + 1], p2 = ep[e + 2], p3 = ep[e + 3];
    float4 v0 = *(const float4*)&h0[(size_t)p0.x * 128 + l * 4];
    float4 v1 = *(const float4*)&h0[(size_t)p1.x * 128 + l * 4];
    float4 v2 = *(const float4*)&h0[(size_t)p2.x * 128 + l * 4];
    float4 v3 = *(const float4*)&h0[(size_t)p3.x * 128 + l * 4];
    float c0 = __int_as_float(p0.y), c1 = __int_as_float(p1.y);
    float c2 = __int_as_float(p2.y), c3 = __int_as_float(p3.y);
    acc.x += v0.x * c0 + v1.x * c1 + v2.x * c2 + v3.x * c3;
    acc.y += v0.y * c0 + v1.y * c1 + v2.y * c2 + v3.y * c3;
    acc.z += v0.z * c0 + v1.z * c1 + v2.z * c2 + v3.z * c3;
    acc.w += v0.w * c0 + v1.w * c1 + v2.w * c2 + v3.w * c3;
  }
  for (; e < end; ++e) {
    int2 pp = ep[e];
    float c = __int_as_float(pp.y);
    float4 v = *(const float4*)&h0[(size_t)pp.x * 128 + l * 4];
    acc.x += v.x * c; acc.y += v.y * c; acc.z += v.z * c; acc.w += v.w * c;
  }
  ((float4*)&h1[(size_t)j * 128])[l] = acc;
  // fused score GEMV
  float4 w4 = ((const float4*)sw)[l];
  float pr = acc.x * w4.x + acc.y * w4.y + acc.z * w4.z + acc.w * w4.w;
#pragma unroll
  for (int off = 16; off; off >>= 1) pr += __shfl_xor(pr, off, 64);
  if (l == 0) spre[j] = pr;
}

// s[j] = spre[j]*dinv^2 + b + sum_e cval*spre[col]  (x4 unrolled, packed edges)
template <int NPER>
static __global__ void k_score2(const float* __restrict__ spre, const float* __restrict__ dinv,
                                const float* __restrict__ bptr, const int* __restrict__ rp,
                                const int2* __restrict__ e2, float* __restrict__ s, int n) {
  int j = blockIdx.x * 256 + threadIdx.x;
  if (j >= n) return;
  int g = j / NPER, li = j - g * NPER;
  const int* rpg = rp + g * (NPER + 1);
  int start = rpg[li], end = rpg[li + 1];
  const int2* ep = e2 + (size_t)g * EPGc;
  float di = dinv[j];
  float acc = spre[j] * di * di + bptr[0];
  int e = start;
  for (; e + 4 <= end; e += 4) {
    int2 p0 = ep[e], p1 = ep[e + 1], p2 = ep[e + 2], p3 = ep[e + 3];
    float a0 = spre[p0.x], a1 = spre[p1.x], a2 = spre[p2.x], a3 = spre[p3.x];
    acc += a0 * __int_as_float(p0.y) + a1 * __int_as_float(p1.y) +
           a2 * __int_as_float(p2.y) + a3 * __int_as_float(p3.y);
  }
  for (; e < end; ++e) { int2 pp = ep[e]; acc += spre[pp.x] * __int_as_float(pp.y); }
  s[j] = acc;
}

// per-graph top-K by bitonic sort of (score, idx) in LDS; only the SET matters downstream
template <int NPER, int K>
static __global__ __launch_bounds__(256) void k_topk(const float* __restrict__ s,
                                                     int* __restrict__ perm) {
  __shared__ float sc[512];
  __shared__ int   idx[512];
  int g = blockIdx.x, tid = threadIdx.x;
  for (int i = tid; i < 512; i += 256) {
    if (i < NPER) { sc[i] = s[g * NPER + i]; idx[i] = i; }
    else          { sc[i] = -3.402823466e38f; idx[i] = 0; }
  }
  __syncthreads();
  for (int kk = 2; kk <= 512; kk <<= 1) {
    for (int j = kk >> 1; j > 0; j >>= 1) {
      for (int base = 0; base < 512; base += 256) {
        int i = base + tid;
        int p = i ^ j;
        if (p > i) {
          bool up = ((i & kk) == 0);          // descending overall
          float si = sc[i], sp = sc[p];
          if (up ? (si < sp) : (si > sp)) {
            sc[i] = sp; sc[p] = si;
            int t = idx[i]; idx[i] = idx[p]; idx[p] = t;
          }
        }
      }
      __syncthreads();
    }
  }
  for (int r = tid; r < K; r += 256) perm[g * K + r] = g * NPER + idx[r];
}

static __global__ void k_remap_scatter(const int* __restrict__ perm, int* __restrict__ remap, int n) {
  int j = blockIdx.x * 256 + threadIdx.x;
  if (j < n) remap[perm[j]] = j;
}

static __global__ void k_edge_remap(const int* __restrict__ src, const int* __restrict__ dst,
                                    const int* __restrict__ remap, int* __restrict__ es,
                                    int* __restrict__ ed, int e) {
  int i = blockIdx.x * 256 + threadIdx.x;
  if (i >= e) return;
  int s2 = remap[src[i]];
  int d2 = remap[dst[i]];
  bool alive = (s2 >= 0) && (d2 >= 0);
  es[i] = alive ? s2 : -1;
  ed[i] = alive ? d2 : -1;
}

// xp[j] = relu(bn( h[perm[j]] * tanh(s[perm[j]]) )); also re-zeroes cnt[j] for next layer
static __global__ __launch_bounds__(128) void k_pool_bn(const float* __restrict__ h,
                                                        const float* __restrict__ s,
                                                        const int* __restrict__ perm,
                                                        const float* __restrict__ gg,
                                                        const float* __restrict__ bb,
                                                        const float* __restrict__ mm,
                                                        const float* __restrict__ vv,
                                                        float* __restrict__ xp,
                                                        int* __restrict__ cnt) {
  int j = blockIdx.x, f = threadIdx.x;
  int old = perm[j];
  float t = tanhf(s[old]);
  float val = h[(size_t)old * 128 + f] * t;
  float o = gg[f] * (val - mm[f]) / sqrtf(vv[f] + EPSc) + bb[f];
  xp[(size_t)j * 128 + f] = fmaxf(o, 0.0f);
  if (f == 0) cnt[j] = 0;
}

// chunked segment-sum
static __global__ __launch_bounds__(128) void k_gsum2(const float* __restrict__ xp,
                                                      float* __restrict__ pooled,
                                                      int nper, int nchunk) {
  int g = blockIdx.x / nchunk, c = blockIdx.x - g * nchunk;
  int f = threadIdx.x;
  int rows = (nper + nchunk - 1) / nchunk;
  int r0 = c * rows;
  int r1 = min(nper, r0 + rows);
  if (r0 >= r1) return;
  float acc = 0.f;
  const float* p = xp + ((size_t)g * nper + r0) * 128 + f;
  for (int i = r0; i < r1; ++i, p += 128) acc += *p;
  atomicAdd(&pooled[g * 128 + f], acc);
}

static __global__ void k_final(const float* __restrict__ pooled,
                               const float* __restrict__ w0, const float* __restrict__ b0,
                               const float* __restrict__ w1, const float* __restrict__ b1,
                               const float* __restrict__ w2, const float* __restrict__ b2,
                               float* __restrict__ out) {
  int t = blockIdx.x * 256 + threadIdx.x;
  if (t >= Bg * DOUTc) return;
  int g = t / DOUTc, o = t - g * DOUTc;
  const float* p0 = pooled + g * 128;
  const float* p1 = pooled + Bg * 128 + g * 128;
  const float* p2 = pooled + 2 * Bg * 128 + g * 128;
  float acc = b0[o] + b1[o] + b2[o];
  for (int k = 0; k < 128; ++k)
    acc += p0[k] * w0[o * 128 + k] + p1[k] * w1[o * 128 + k] + p2[k] * w2[o * 128 + k];
  out[t] = acc;
}

extern "C" void kernel_launch(void* const* d_in, const int* in_sizes, int n_in,
                              void* d_out, int out_size, void* d_ws, size_t ws_size,
                              hipStream_t stream) {
  (void)in_sizes; (void)n_in; (void)out_size; (void)ws_size;
  const float* x    = (const float*)d_in[0];
  const int*   ei   = (const int*)d_in[1];
  const int*   src0 = ei;
  const int*   dst0 = ei + Etot;
  const float* c1W = (const float*)d_in[2];  const float* c1b = (const float*)d_in[3];
  const float* c2W = (const float*)d_in[4];  const float* c2b = (const float*)d_in[5];
  const float* s1W = (const float*)d_in[6];  const float* s1b = (const float*)d_in[7];
  const float* s2W = (const float*)d_in[8];  const float* s2b = (const float*)d_in[9];
  const float* bn1g = (const float*)d_in[10]; const float* bn1b = (const float*)d_in[11];
  const float* bn1m = (const float*)d_in[12]; const float* bn1v = (const float*)d_in[13];
  const float* bn2g = (const float*)d_in[14]; const float* bn2b = (const float*)d_in[15];
  const float* bn2m = (const float*)d_in[16]; const float* bn2v = (const float*)d_in[17];
  const float* l0W = (const float*)d_in[18]; const float* l0b = (const float*)d_in[19];
  const float* l1W = (const float*)d_in[20]; const float* l1b = (const float*)d_in[21];
  const float* l2W = (const float*)d_in[22]; const float* l2b = (const float*)d_in[23];
  float* out = (float*)d_out;

  char* p = (char*)d_ws;
  auto alloc = [&](size_t bytes) { char* q = p; p += (bytes + 255) & ~(size_t)255; return q; };
  float* h0    = (float*)alloc((size_t)N0c * 128 * 4);   // layer1 reuses as g1
  float* h1    = (float*)alloc((size_t)N0c * 128 * 4);   // layer1 reuses as h2
  float* xp1   = (float*)alloc((size_t)N1c * 128 * 4);
  float* xp2   = (float*)alloc((size_t)N2c * 128 * 4);
  int*   cnt   = (int*)alloc((size_t)N0c * 4);           // also the CSR scatter counter
  float* dinv  = (float*)alloc((size_t)N0c * 4);
  int*   rp    = (int*)alloc((size_t)Bg * (NPG + 1) * 4);
  int2*  e2    = (int2*)alloc((size_t)Etot * 8);
  float* spre  = (float*)alloc((size_t)N0c * 4);
  float* sv    = (float*)alloc((size_t)N0c * 4);
  int*   perm  = (int*)alloc((size_t)N1c * 4);
  int*   remap = (int*)alloc((size_t)N0c * 4);
  int*   es    = (int*)alloc((size_t)Etot * 4);
  int*   ed    = (int*)alloc((size_t)Etot * 4);
  float* pooled= (float*)alloc((size_t)3 * Bg * 128 * 4);

  dim3 b256(256), b128(128), b512(512);
  int gE = (Etot + 255) / 256;

  // ---------------- layer 0 ----------------
  k_init<<<(N0c + 255) / 256, b256, 0, stream>>>(cnt, remap, pooled);
  k_cnt<<<gE, b256, 0, stream>>>(dst0, cnt, Etot);
  k_dinv<<<(N0c + 255) / 256, b256, 0, stream>>>(cnt, dinv, N0c);
  k_rowscan<<<Bg, b512, 0, stream>>>(cnt, rp, NPG);            // zeroes cnt
  k_fill_csr<<<gE, b256, 0, stream>>>(src0, dst0, dinv, rp, cnt, e2, NPG, Etot);
  k_gemm2<<<N0c / 128, b512, 0, stream>>>(x, c1W, h0, N0c);
  k_agg3<NPG, 64><<<128 * 64, b256, 0, stream>>>(h0, dinv, c1b, rp, e2, s1W, h1, spre);
  k_score2<NPG><<<(N0c + 255) / 256, b256, 0, stream>>>(spre, dinv, s1b, rp, e2, sv, N0c);
  k_topk<NPG, K1c><<<Bg, b256, 0, stream>>>(sv, perm);
  k_remap_scatter<<<(N1c + 255) / 256, b256, 0, stream>>>(perm, remap, N1c);
  k_edge_remap<<<gE, b256, 0, stream>>>(src0, dst0, remap, es, ed, Etot);
  k_pool_bn<<<N1c, b128, 0, stream>>>(h1, sv, perm, bn1g, bn1b, bn1m, bn1v, xp1, cnt);

  // ---------------- layer 1 ----------------
  k_cnt<<<gE, b256, 0, stream>>>(ed, cnt, Etot);               // cnt zeroed by pool_bn
  k_dinv<<<(N1c + 255) / 256, b256, 0, stream>>>(cnt, dinv, N1c);
  k_rowscan<<<Bg, b512, 0, stream>>>(cnt, rp, K1c);            // zeroes cnt
  k_fill_csr<<<gE, b256, 0, stream>>>(es, ed, dinv, rp, cnt, e2, K1c, Etot);
  float* g1 = h0;   // h0 dead after layer-0 agg
  float* h2 = h1;   // h1 dead after pool_bn
  k_gemm2<<<N1c / 128, b512, 0, stream>>>(xp1, c2W, g1, N1c);
  k_agg3<K1c, 52><<<128 * 52, b256, 0, stream>>>(g1, dinv, c2b, rp, e2, s2W, h2, spre);
  k_score2<K1c><<<(N1c + 255) / 256, b256, 0, stream>>>(spre, dinv, s2b, rp, e2, sv, N1c);
  k_topk<K1c, K2c><<<Bg, b256, 0, stream>>>(sv, perm);
  k_pool_bn<<<N2c, b128, 0, stream>>>(h2, sv, perm, bn2g, bn2b, bn2m, bn2v, xp2, cnt);

  // ---------------- readout ----------------
  k_gsum2<<<Bg * 16, b128, 0, stream>>>(x, pooled, NPG, 16);
  k_gsum2<<<Bg * 16, b128, 0, stream>>>(xp1, pooled + Bg * 128, K1c, 16);
  k_gsum2<<<Bg * 16, b128, 0, stream>>>(xp2, pooled + 2 * Bg * 128, K2c, 16);
  k_final<<<(Bg * DOUTc + 255) / 256, b256, 0, stream>>>(pooled, l0W, l0b, l1W, l1b, l2W, l2b, out);
}

// Round 6
// 394.588 us; speedup vs baseline: 1.9780x; 1.2186x over previous
//
#include <hip/hip_runtime.h>

#define Bg   128
#define NPG  512
#define EPGc 8192
#define Etot (Bg*EPGc)
#define DOUTc 10
#define K1c  410
#define K2c  328
#define N0c  (Bg*NPG)
#define N1c  (Bg*K1c)
#define N2c  (Bg*K2c)
#define EPSc 1e-5f

// ---------------- layer-0 graph prep, fully fused per graph ----------------
// block g: zero pooled slices; count in-degree in LDS; dinv; exclusive scan;
// scatter packed CSR records. Replaces init+cnt+dinv+rowscan+fill_csr (5 dispatches,
// all-global atomics) with one 128-block kernel using LDS atomics.
static __global__ __launch_bounds__(512) void k_prep0(const int* __restrict__ src,
                                                      const int* __restrict__ dst,
                                                      float* __restrict__ dinv,
                                                      int* __restrict__ rp,
                                                      int2* __restrict__ e2,
                                                      float* __restrict__ pooled) {
  __shared__ int   cnt[NPG];
  __shared__ float sdv[NPG];
  __shared__ int   srp[NPG];
  __shared__ int   sbuf[512];
  int g = blockIdx.x, tid = threadIdx.x;
  if (tid < 128) {
    pooled[g * 128 + tid] = 0.f;
    pooled[Bg * 128 + g * 128 + tid] = 0.f;
    pooled[2 * Bg * 128 + g * 128 + tid] = 0.f;
  }
  cnt[tid] = 0;
  __syncthreads();
  const int* sp = src + (size_t)g * EPGc;
  const int* dp = dst + (size_t)g * EPGc;
  for (int e = tid; e < EPGc; e += 512) atomicAdd(&cnt[dp[e] - g * NPG], 1);
  __syncthreads();
  int c = cnt[tid];
  float dv = 1.0f / sqrtf(1.0f + (float)c);
  sdv[tid] = dv;
  dinv[g * NPG + tid] = dv;
  sbuf[tid] = c;
  __syncthreads();
  for (int off = 1; off < 512; off <<= 1) {
    int t = (tid >= off) ? sbuf[tid - off] : 0;
    __syncthreads();
    sbuf[tid] += t;
    __syncthreads();
  }
  srp[tid] = sbuf[tid] - c;
  rp[g * (NPG + 1) + tid] = sbuf[tid] - c;
  if (tid == 511) rp[g * (NPG + 1) + NPG] = sbuf[511];
  cnt[tid] = 0;
  __syncthreads();
  for (int e = tid; e < EPGc; e += 512) {
    int s = sp[e], d = dp[e];
    int dl = d - g * NPG;
    int pos = srp[dl] + atomicAdd(&cnt[dl], 1);
    e2[(size_t)g * EPGc + pos] =
        make_int2(s, __float_as_int(sdv[s - g * NPG] * sdv[dl]));
  }
}

// ---------------- GEMM: Y[M x 128] = X[M x 128] @ W[128 x 128] ----------------
// Round-5 fix: thread's 8 cols split into two float4 groups at tx*4 and 64+tx*4 ->
// 16 lanes read 256 contiguous B -> bank-tiling perfect (2-way = free). Old tx*8
// layout was 4-way conflicted on every W read (4.19e6 conflicts/dispatch).
static __global__ __launch_bounds__(512) void k_gemm2(const float* __restrict__ X,
                                                      const float* __restrict__ W,
                                                      float* __restrict__ Y, int M) {
  __shared__ float ws[128 * 128];      // 64 KB, [k][n]
  __shared__ float xs[128 * 132];      // 66 KB, [r][k] padded +4
  int tid = threadIdx.x;
  for (int i = tid; i < 4096; i += 512) ((float4*)ws)[i] = ((const float4*)W)[i];
  int row0 = blockIdx.x * 128;
  for (int i = tid; i < 4096; i += 512) {
    int r = i >> 5, kq = i & 31;
    float4 v = ((const float4*)X)[(size_t)(row0 + r) * 32 + kq];
    *(float4*)&xs[r * 132 + kq * 4] = v;
  }
  __syncthreads();
  int tx = tid & 15, ty = tid >> 4;    // rows ty*4..+3; cols {tx*4..+3, 64+tx*4..+3}
  float acc[4][8];
#pragma unroll
  for (int i = 0; i < 4; ++i)
#pragma unroll
    for (int j = 0; j < 8; ++j) acc[i][j] = 0.f;
  for (int k = 0; k < 128; k += 4) {
    float4 xr[4];
#pragma unroll
    for (int i = 0; i < 4; ++i) xr[i] = *(const float4*)&xs[(ty * 4 + i) * 132 + k];
    const float* xf = (const float*)xr;
#pragma unroll
    for (int kk = 0; kk < 4; ++kk) {
      float4 wa = *(const float4*)&ws[(k + kk) * 128 + tx * 4];
      float4 wb = *(const float4*)&ws[(k + kk) * 128 + 64 + tx * 4];
#pragma unroll
      for (int i = 0; i < 4; ++i) {
        float xv = xf[i * 4 + kk];
        acc[i][0] += xv * wa.x; acc[i][1] += xv * wa.y;
        acc[i][2] += xv * wa.z; acc[i][3] += xv * wa.w;
        acc[i][4] += xv * wb.x; acc[i][5] += xv * wb.y;
        acc[i][6] += xv * wb.z; acc[i][7] += xv * wb.w;
      }
    }
  }
#pragma unroll
  for (int i = 0; i < 4; ++i) {
    int row = row0 + ty * 4 + i;
    float4 o1 = make_float4(acc[i][0], acc[i][1], acc[i][2], acc[i][3]);
    float4 o2 = make_float4(acc[i][4], acc[i][5], acc[i][6], acc[i][7]);
    ((float4*)Y)[(size_t)row * 32 + tx] = o1;
    ((float4*)Y)[(size_t)row * 32 + 16 + tx] = o2;
  }
}

// GCN aggregation: high-occupancy L2 gather with 4x edge MLP + fused score GEMV.
template <int NPER, int RG>
static __global__ __launch_bounds__(256) void k_agg3(const float* __restrict__ h0,
                                                     const float* __restrict__ dinv,
                                                     const float* __restrict__ bias,
                                                     const int* __restrict__ rp,
                                                     const int2* __restrict__ e2,
                                                     const float* __restrict__ sw,
                                                     float* __restrict__ h1,
                                                     float* __restrict__ spre) {
  int tid = threadIdx.x;
  int hw = tid >> 5, l = tid & 31;
  int b = blockIdx.x;
  int xcd = b & 7, slot = b >> 3;
  int g = xcd * 16 + (slot & 15);
  int rowgrp = slot >> 4;                 // [0, RG)
  int li = rowgrp * 8 + hw;
  if (li >= NPER) return;
  int j = g * NPER + li;
  const int* rpg = rp + g * (NPER + 1);
  int start = rpg[li], end = rpg[li + 1];
  const int2* ep = e2 + (size_t)g * EPGc;
  float di = dinv[j];
  float sc = di * di;
  float4 acc = *(const float4*)&h0[(size_t)j * 128 + l * 4];
  float4 bb = ((const float4*)bias)[l];
  acc.x = acc.x * sc + bb.x; acc.y = acc.y * sc + bb.y;
  acc.z = acc.z * sc + bb.z; acc.w = acc.w * sc + bb.w;
  int e = start;
  for (; e + 4 <= end; e += 4) {
    int2 p0 = ep[e], p1 = ep[e + 1], p2 = ep[e + 2], p3 = ep[e + 3];
    float4 v0 = *(const float4*)&h0[(size_t)p0.x * 128 + l * 4];
    float4 v1 = *(const float4*)&h0[(size_t)p1.x * 128 + l * 4];
    float4 v2 = *(const float4*)&h0[(size_t)p2.x * 128 + l * 4];
    float4 v3 = *(const float4*)&h0[(size_t)p3.x * 128 + l * 4];
    float c0 = __int_as_float(p0.y), c1 = __int_as_float(p1.y);
    float c2 = __int_as_float(p2.y), c3 = __int_as_float(p3.y);
    acc.x += v0.x * c0 + v1.x * c1 + v2.x * c2 + v3.x * c3;
    acc.y += v0.y * c0 + v1.y * c1 + v2.y * c2 + v3.y * c3;
    acc.z += v0.z * c0 + v1.z * c1 + v2.z * c2 + v3.z * c3;
    acc.w += v0.w * c0 + v1.w * c1 + v2.w * c2 + v3.w * c3;
  }
  for (; e < end; ++e) {
    int2 pp = ep[e];
    float c = __int_as_float(pp.y);
    float4 v = *(const float4*)&h0[(size_t)pp.x * 128 + l * 4];
    acc.x += v.x * c; acc.y += v.y * c; acc.z += v.z * c; acc.w += v.w * c;
  }
  ((float4*)&h1[(size_t)j * 128])[l] = acc;
  // fused score GEMV
  float4 w4 = ((const float4*)sw)[l];
  float pr = acc.x * w4.x + acc.y * w4.y + acc.z * w4.z + acc.w * w4.w;
#pragma unroll
  for (int off = 16; off; off >>= 1) pr += __shfl_xor(pr, off, 64);
  if (l == 0) spre[j] = pr;
}

// s[j] = spre[j]*dinv^2 + b + sum_e cval*spre[col]  (x4 unrolled, packed edges)
template <int NPER>
static __global__ void k_score2(const float* __restrict__ spre, const float* __restrict__ dinv,
                                const float* __restrict__ bptr, const int* __restrict__ rp,
                                const int2* __restrict__ e2, float* __restrict__ s, int n) {
  int j = blockIdx.x * 256 + threadIdx.x;
  if (j >= n) return;
  int g = j / NPER, li = j - g * NPER;
  const int* rpg = rp + g * (NPER + 1);
  int start = rpg[li], end = rpg[li + 1];
  const int2* ep = e2 + (size_t)g * EPGc;
  float di = dinv[j];
  float acc = spre[j] * di * di + bptr[0];
  int e = start;
  for (; e + 4 <= end; e += 4) {
    int2 p0 = ep[e], p1 = ep[e + 1], p2 = ep[e + 2], p3 = ep[e + 3];
    float a0 = spre[p0.x], a1 = spre[p1.x], a2 = spre[p2.x], a3 = spre[p3.x];
    acc += a0 * __int_as_float(p0.y) + a1 * __int_as_float(p1.y) +
           a2 * __int_as_float(p2.y) + a3 * __int_as_float(p3.y);
  }
  for (; e < end; ++e) { int2 pp = ep[e]; acc += spre[pp.x] * __int_as_float(pp.y); }
  s[j] = acc;
}

// ---------------- repool: topk + remap + edge filter + CSR build, per graph ------
// block g: bitonic-sort scores (512 thr), take top-K set, remap old->new in LDS,
// 2-pass over the ORIGINAL edge slot (count -> scan -> scatter). Replaces
// topk+remap_scatter+edge_remap+cnt+dinv+rowscan+fill_csr (7 dispatches) and never
// materializes es/ed (saves 24 MB of global traffic).
template <int NPER, int K>
static __global__ __launch_bounds__(512) void k_repool(const float* __restrict__ sv,
                                                       const int* __restrict__ src,
                                                       const int* __restrict__ dst,
                                                       int* __restrict__ perm,
                                                       float* __restrict__ dinv,
                                                       int* __restrict__ rp,
                                                       int2* __restrict__ e2) {
  __shared__ float sc[512];
  __shared__ int   sidx[512];
  __shared__ short remap[NPER];
  __shared__ int   cnt[K];
  __shared__ float sdv[K];
  __shared__ int   srp[K];
  __shared__ int   sbuf[512];
  int g = blockIdx.x, tid = threadIdx.x;
  sc[tid] = (tid < NPER) ? sv[g * NPER + tid] : -3.402823466e38f;
  sidx[tid] = tid;
  if (tid < NPER) remap[tid] = -1;
  __syncthreads();
  for (int kk = 2; kk <= 512; kk <<= 1) {
    for (int j = kk >> 1; j > 0; j >>= 1) {
      int i = tid, p = i ^ j;
      if (p > i) {
        bool up = ((i & kk) == 0);          // descending overall
        float si = sc[i], sp2 = sc[p];
        if (up ? (si < sp2) : (si > sp2)) {
          sc[i] = sp2; sc[p] = si;
          int t = sidx[i]; sidx[i] = sidx[p]; sidx[p] = t;
        }
      }
      __syncthreads();
    }
  }
  if (tid < K) {
    perm[g * K + tid] = g * NPER + sidx[tid];
    remap[sidx[tid]] = (short)tid;
    cnt[tid] = 0;
  }
  __syncthreads();
  const int* sp = src + (size_t)g * EPGc;
  const int* dp = dst + (size_t)g * EPGc;
  for (int e = tid; e < EPGc; e += 512) {
    int s = remap[sp[e] - g * NPER];
    int d = remap[dp[e] - g * NPER];
    if (s >= 0 && d >= 0) atomicAdd(&cnt[d], 1);
  }
  __syncthreads();
  int c = (tid < K) ? cnt[tid] : 0;
  if (tid < K) {
    float dv = 1.0f / sqrtf(1.0f + (float)c);
    sdv[tid] = dv;
    dinv[g * K + tid] = dv;
  }
  sbuf[tid] = c;
  __syncthreads();
  for (int off = 1; off < 512; off <<= 1) {
    int t = (tid >= off) ? sbuf[tid - off] : 0;
    __syncthreads();
    sbuf[tid] += t;
    __syncthreads();
  }
  if (tid < K) { srp[tid] = sbuf[tid] - c; rp[g * (K + 1) + tid] = sbuf[tid] - c; cnt[tid] = 0; }
  if (tid == 511) rp[g * (K + 1) + K] = sbuf[511];
  __syncthreads();
  for (int e = tid; e < EPGc; e += 512) {
    int s = remap[sp[e] - g * NPER];
    int d = remap[dp[e] - g * NPER];
    if (s >= 0 && d >= 0) {
      int pos = srp[d] + atomicAdd(&cnt[d], 1);
      e2[(size_t)g * EPGc + pos] = make_int2(g * K + s, __float_as_int(sdv[s] * sdv[d]));
    }
  }
}

// plain per-graph top-K (layer 2 needs no edge rebuild)
template <int NPER, int K>
static __global__ __launch_bounds__(256) void k_topk(const float* __restrict__ s,
                                                     int* __restrict__ perm) {
  __shared__ float sc[512];
  __shared__ int   idx[512];
  int g = blockIdx.x, tid = threadIdx.x;
  for (int i = tid; i < 512; i += 256) {
    if (i < NPER) { sc[i] = s[g * NPER + i]; idx[i] = i; }
    else          { sc[i] = -3.402823466e38f; idx[i] = 0; }
  }
  __syncthreads();
  for (int kk = 2; kk <= 512; kk <<= 1) {
    for (int j = kk >> 1; j > 0; j >>= 1) {
      for (int base = 0; base < 512; base += 256) {
        int i = base + tid;
        int p = i ^ j;
        if (p > i) {
          bool up = ((i & kk) == 0);
          float si = sc[i], sp = sc[p];
          if (up ? (si < sp) : (si > sp)) {
            sc[i] = sp; sc[p] = si;
            int t = idx[i]; idx[i] = idx[p]; idx[p] = t;
          }
        }
      }
      __syncthreads();
    }
  }
  for (int r = tid; r < K; r += 256) perm[g * K + r] = g * NPER + idx[r];
}

// xp[j] = relu(bn(h[perm[j]]*tanh(s[perm[j]]))), fused global_add_pool:
// per-block local row-chunk accumulate, one atomic per feature.
template <int NPER, int CH>
static __global__ __launch_bounds__(128) void k_poolbn(const float* __restrict__ h,
                                                       const float* __restrict__ s,
                                                       const int* __restrict__ perm,
                                                       const float* __restrict__ gg,
                                                       const float* __restrict__ bb,
                                                       const float* __restrict__ mm,
                                                       const float* __restrict__ vv,
                                                       float* __restrict__ xp,
                                                       float* __restrict__ pooledseg) {
  int g = blockIdx.x / CH, cidx = blockIdx.x - g * CH;
  int f = threadIdx.x;
  const int rows = (NPER + CH - 1) / CH;
  int r0 = cidx * rows, r1 = min(NPER, r0 + rows);
  float G = gg[f], Bb = bb[f], Mm = mm[f];
  float inv = 1.0f / sqrtf(vv[f] + EPSc);
  float acc = 0.f;
  for (int r = r0; r < r1; ++r) {
    int j = g * NPER + r;
    int old = perm[j];
    float t = tanhf(s[old]);
    float val = h[(size_t)old * 128 + f] * t;
    float o = G * (val - Mm) * inv + Bb;
    o = fmaxf(o, 0.0f);
    xp[(size_t)j * 128 + f] = o;
    acc += o;
  }
  atomicAdd(&pooledseg[g * 128 + f], acc);
}

// chunked segment-sum for the raw-x readout
static __global__ __launch_bounds__(128) void k_gsum2(const float* __restrict__ xp,
                                                      float* __restrict__ pooled,
                                                      int nper, int nchunk) {
  int g = blockIdx.x / nchunk, c = blockIdx.x - g * nchunk;
  int f = threadIdx.x;
  int rows = (nper + nchunk - 1) / nchunk;
  int r0 = c * rows;
  int r1 = min(nper, r0 + rows);
  if (r0 >= r1) return;
  float acc = 0.f;
  const float* p = xp + ((size_t)g * nper + r0) * 128 + f;
  for (int i = r0; i < r1; ++i, p += 128) acc += *p;
  atomicAdd(&pooled[g * 128 + f], acc);
}

static __global__ void k_final(const float* __restrict__ pooled,
                               const float* __restrict__ w0, const float* __restrict__ b0,
                               const float* __restrict__ w1, const float* __restrict__ b1,
                               const float* __restrict__ w2, const float* __restrict__ b2,
                               float* __restrict__ out) {
  int t = blockIdx.x * 256 + threadIdx.x;
  if (t >= Bg * DOUTc) return;
  int g = t / DOUTc, o = t - g * DOUTc;
  const float* p0 = pooled + g * 128;
  const float* p1 = pooled + Bg * 128 + g * 128;
  const float* p2 = pooled + 2 * Bg * 128 + g * 128;
  float acc = b0[o] + b1[o] + b2[o];
  for (int k = 0; k < 128; ++k)
    acc += p0[k] * w0[o * 128 + k] + p1[k] * w1[o * 128 + k] + p2[k] * w2[o * 128 + k];
  out[t] = acc;
}

extern "C" void kernel_launch(void* const* d_in, const int* in_sizes, int n_in,
                              void* d_out, int out_size, void* d_ws, size_t ws_size,
                              hipStream_t stream) {
  (void)in_sizes; (void)n_in; (void)out_size; (void)ws_size;
  const float* x    = (const float*)d_in[0];
  const int*   ei   = (const int*)d_in[1];
  const int*   src0 = ei;
  const int*   dst0 = ei + Etot;
  const float* c1W = (const float*)d_in[2];  const float* c1b = (const float*)d_in[3];
  const float* c2W = (const float*)d_in[4];  const float* c2b = (const float*)d_in[5];
  const float* s1W = (const float*)d_in[6];  const float* s1b = (const float*)d_in[7];
  const float* s2W = (const float*)d_in[8];  const float* s2b = (const float*)d_in[9];
  const float* bn1g = (const float*)d_in[10]; const float* bn1b = (const float*)d_in[11];
  const float* bn1m = (const float*)d_in[12]; const float* bn1v = (const float*)d_in[13];
  const float* bn2g = (const float*)d_in[14]; const float* bn2b = (const float*)d_in[15];
  const float* bn2m = (const float*)d_in[16]; const float* bn2v = (const float*)d_in[17];
  const float* l0W = (const float*)d_in[18]; const float* l0b = (const float*)d_in[19];
  const float* l1W = (const float*)d_in[20]; const float* l1b = (const float*)d_in[21];
  const float* l2W = (const float*)d_in[22]; const float* l2b = (const float*)d_in[23];
  float* out = (float*)d_out;

  char* p = (char*)d_ws;
  auto alloc = [&](size_t bytes) { char* q = p; p += (bytes + 255) & ~(size_t)255; return q; };
  float* h0    = (float*)alloc((size_t)N0c * 128 * 4);   // layer1 reuses as g1
  float* h1    = (float*)alloc((size_t)N0c * 128 * 4);   // layer1 reuses as h2
  float* xp1   = (float*)alloc((size_t)N1c * 128 * 4);
  float* xp2   = (float*)alloc((size_t)N2c * 128 * 4);
  float* dinv  = (float*)alloc((size_t)N0c * 4);
  int*   rp    = (int*)alloc((size_t)Bg * (NPG + 1) * 4);
  int2*  e2    = (int2*)alloc((size_t)Etot * 8);
  float* spre  = (float*)alloc((size_t)N0c * 4);
  float* sv    = (float*)alloc((size_t)N0c * 4);
  int*   perm  = (int*)alloc((size_t)N1c * 4);
  float* pooled= (float*)alloc((size_t)3 * Bg * 128 * 4);

  dim3 b256(256), b128(128), b512(512);

  // ---------------- layer 0 ----------------
  k_prep0<<<Bg, b512, 0, stream>>>(src0, dst0, dinv, rp, e2, pooled);
  k_gemm2<<<N0c / 128, b512, 0, stream>>>(x, c1W, h0, N0c);
  k_agg3<NPG, 64><<<128 * 64, b256, 0, stream>>>(h0, dinv, c1b, rp, e2, s1W, h1, spre);
  k_score2<NPG><<<(N0c + 255) / 256, b256, 0, stream>>>(spre, dinv, s1b, rp, e2, sv, N0c);
  k_repool<NPG, K1c><<<Bg, b512, 0, stream>>>(sv, src0, dst0, perm, dinv, rp, e2);
  k_poolbn<K1c, 8><<<Bg * 8, b128, 0, stream>>>(h1, sv, perm, bn1g, bn1b, bn1m, bn1v,
                                                xp1, pooled + Bg * 128);

  // ---------------- layer 1 ----------------
  float* g1 = h0;   // h0 dead after layer-0 agg
  float* h2 = h1;   // h1 dead after poolbn
  k_gemm2<<<N1c / 128, b512, 0, stream>>>(xp1, c2W, g1, N1c);
  k_agg3<K1c, 52><<<128 * 52, b256, 0, stream>>>(g1, dinv, c2b, rp, e2, s2W, h2, spre);
  k_score2<K1c><<<(N1c + 255) / 256, b256, 0, stream>>>(spre, dinv, s2b, rp, e2, sv, N1c);
  k_topk<K1c, K2c><<<Bg, b256, 0, stream>>>(sv, perm);
  k_poolbn<K2c, 8><<<Bg * 8, b128, 0, stream>>>(h2, sv, perm, bn2g, bn2b, bn2m, bn2v,
                                                xp2, pooled + 2 * Bg * 128);

  // ---------------- readout ----------------
  k_gsum2<<<Bg * 16, b128, 0, stream>>>(x, pooled, NPG, 16);
  k_final<<<(Bg * DOUTc + 255) / 256, b256, 0, stream>>>(pooled, l0W, l0b, l1W, l1b, l2W, l2b, out);
}